// Round 7
// baseline (129.530 us; speedup 1.0000x reference)
//
#include <hip/hip_runtime.h>

// InverseBarkScale: 30-iter SGD with momentum inverting a bark filterbank.
// fb (513x128): freq f has taps only at columns (k1(f), k1(f)+1); k1 is
// monotone in f, so P(c) = {f : k1(f)=c} are contiguous and partition
// [0,513). |P(c)| <= ~3 for c<64, <= ~18 for c>=64.
//
// R7: iter_kernel was ~42us since R4, VALUBusy 39% at 2 waves/SIMD ->
// each wave stalled ~80%: 8 dependent DS-permute rounds per iteration
// (carry shfl + 6-deep loss reduction + dAn/dBn) at ~120cyc DS latency.
// This round: same math, DS latency hidden:
//  - loss reduction DEFERRED one iteration (runs during next iter's FMAs)
//  - carry shfls issued before the 26 independent sAA/sAB FMAs
//  - momentum decay h=0.9*bf (26 indep muls) hides the dAn/dBn shfls
//  - #pragma unroll 2 on the it-loop for a wider scheduling window
// Structure unchanged otherwise: all-register, lane owns cols (l,127-l) and
// their primary freqs; no LDS, no barriers; speculate-30 + loss log -> scan
// computes stop iteration S -> repair launch only if S<30 (immediate exit
// expected). Known floor: harness d_ws poison fill + input restore + graph
// gaps ~= 65us of dur; not controllable.

#define NSTFT 513
#define NBARK 128
#define BATCH 4
#define TIME  512
#define MAXIT 30
#define NROWS (BATCH*TIME)      // 2048 rows, 1 wave each
#define SA 6                    // A-side slots (cols 0..63, max ~3 real)
#define SB 20                   // B-side slots (cols 64..127, max ~18 real)

// d_ws layout (bytes); ~260 KB. Every field written before read each call.
#define WS_S_OFF   0                          // int: stop iteration S
#define WS_HA_OFF  256                        // int2[64]: A {fbase,cnt}
#define WS_HB_OFF  768                        // int2[64]: B {fbase,cnt}
#define WS_WT_OFF  1280                       // float2[SA+SB][64]: {w1,w2}
#define WS_BP_OFF  14848                      // float[MAXIT][NROWS] partials

// ---- setup: taps (wave-ballot) + partition + lane tables, one block ----
__global__ __launch_bounds__(512) void setup_all(const float* __restrict__ fb,
                                                 char* __restrict__ ws) {
    __shared__ short  k1s[NSTFT];        // primary column per freq
    __shared__ float2 swt[NSTFT];        // {w1,w2} per freq
    __shared__ int    fstart[NBARK + 1]; // P(c) = [fstart[c], fstart[c+1])
    const int tid = threadIdx.x, wave = tid >> 6, lane = tid & 63;

    // phase A: per-freq taps. Wave handles f = wave + 8*step; lane loads
    // float2 covering k = 2*lane, 2*lane+1 (one coalesced 512B load/row).
#pragma unroll 4
    for (int f = wave; f < NSTFT; f += 8) {
        const float2 v = ((const float2*)(fb + (size_t)f * NBARK))[lane];
        unsigned long long mx = __ballot(v.x > 0.f);
        unsigned long long my = __ballot(v.y > 0.f);
        int kx = mx ? 2 * (__ffsll(mx) - 1)     : 999;
        int ky = my ? 2 * (__ffsll(my) - 1) + 1 : 999;
        int k1 = min(kx, ky);
        float w1 = 0.f, w2 = 0.f;
        if (k1 < NBARK) {
            float sx = __shfl(v.x, k1 >> 1);
            float sy = __shfl(v.y, k1 >> 1);
            w1 = (k1 & 1) ? sy : sx;
            const int k2 = k1 + 1;               // taps are consecutive cols
            if (k2 < NBARK) {
                float tx = __shfl(v.x, k2 >> 1);
                float ty = __shfl(v.y, k2 >> 1);
                w2 = (k2 & 1) ? ty : tx;         // ==0 if row has 1 tap
            }
        } else {
            k1 = (f < 256) ? 0 : 127;            // all-zero row: edge attach
        }
        if (lane == 0) { k1s[f] = (short)k1; swt[f] = make_float2(w1, w2); }
    }
    __syncthreads();

    // phase B1: fstart via k1-crossings (k1 monotone; each c written once)
    for (int f = tid; f < NSTFT; f += 512) {
        int kprev = (f == 0) ? -1 : (int)k1s[f - 1];
        int kcur  = (int)k1s[f];
        for (int c = kprev + 1; c <= kcur; ++c) fstart[c] = f;
    }
    if (tid == 0) fstart[NBARK] = NSTFT;
    __syncthreads();

    // phase B2: per-lane headers
    if (tid < NBARK) {
        const int c   = tid;
        const int cap = (c < 64) ? SA : SB;
        const int lf  = (c < 64) ? c  : 127 - c;
        int cnt = fstart[c + 1] - fstart[c];
        cnt = min(cnt, cap);
        ((int2*)(ws + (c < 64 ? WS_HA_OFF : WS_HB_OFF)))[lf] =
            make_int2(fstart[c], cnt);
    }
    // phase B3: packed weight tables (zero pads beyond cnt)
    float2* wt = (float2*)(ws + WS_WT_OFF);
    for (int t = tid; t < 64 * (SA + SB); t += 512) {
        const int slot = t >> 6, l = t & 63;
        const bool Aside = (slot < SA);
        const int c   = Aside ? l : 127 - l;
        const int i   = Aside ? slot : slot - SA;
        const int cap = Aside ? SA : SB;
        const int fs  = fstart[c];
        int cnt = min(fstart[c + 1] - fs, cap);
        wt[slot * 64 + l] = (i < cnt) ? swt[fs + i] : make_float2(0.f, 0.f);
    }
}

__global__ __launch_bounds__(64, 2) void
iter_kernel(const float* __restrict__ barkspec,
            const float* __restrict__ spec_init,
            float* __restrict__ out,
            char* __restrict__ ws, int mode)
{
    const int lane = threadIdx.x;            // single wave per block, no LDS

    int niter = MAXIT;
    if (mode) {
        int S = *(const volatile int*)(ws + WS_S_OFF);
        if (S >= MAXIT) return;              // expected path: no repair
        niter = S;
    }

    const int r     = blockIdx.x;
    const int batch = r >> 9;
    const int t     = r & (TIME - 1);

    // ---- per-lane tables -> registers ----
    const int2 hA = ((const int2*)(ws + WS_HA_OFF))[lane];
    const int2 hB = ((const int2*)(ws + WS_HB_OFF))[lane];
    const float2* wt = (const float2*)(ws + WS_WT_OFF);
    const float* spg = spec_init + ((size_t)batch*TIME + t)*NSTFT;

    float w1A[SA], w2A[SA], spA[SA], bfA[SA];
    float w1B[SB], w2B[SB], spB[SB], bfB[SB];
#pragma unroll
    for (int i = 0; i < SA; ++i) {
        float2 v = wt[i*64 + lane];
        w1A[i] = v.x; w2A[i] = v.y;
        spA[i] = (i < hA.y) ? spg[hA.x + i] : 0.f;
        bfA[i] = 0.f;
    }
#pragma unroll
    for (int i = 0; i < SB; ++i) {
        float2 v = wt[(SA + i)*64 + lane];
        w1B[i] = v.x; w2B[i] = v.y;
        spB[i] = (i < hB.y) ? spg[hB.x + i] : 0.f;
        bfB[i] = 0.f;
    }

    const float* bs = barkspec + (size_t)batch*NBARK*TIME + t;
    const float m0 = bs[(size_t)lane*TIME];          // col cA = lane
    const float m1 = bs[(size_t)(127 - lane)*TIME];  // col cB = 127-lane

    float* bp = (float*)(ws + WS_BP_OFF);
    const float GC = -2.0f / (float)NROWS;

    float lp_prev = 0.f;                     // loss partial of iteration it-1

#pragma unroll 2
    for (int it = 0; it < niter; ++it) {
        // ---- forward, carry-producing sums FIRST; issue their shfls early
        float sBA = 0.f, sBB = 0.f;
#pragma unroll
        for (int i = 0; i < SA; ++i) sBA = fmaf(spA[i], w2A[i], sBA);
#pragma unroll
        for (int i = 0; i < SB; ++i) sBB = fmaf(spB[i], w2B[i], sBB);
        float cAin = __shfl_up(sBA, 1);      // latency hidden under sAA/sAB
        float cBin = __shfl_down(sBB, 1);

        // ---- deferred loss reduction of iter it-1 (independent of iter it)
        if (!mode && it > 0) {
            float lp = lp_prev;
#pragma unroll
            for (int m = 32; m; m >>= 1) lp += __shfl_xor(lp, m);
            if (lane == 0) bp[(it - 1)*NROWS + r] = lp;  // fire-and-forget
        }

        float sAA = 0.f, sAB = 0.f;
#pragma unroll
        for (int i = 0; i < SA; ++i) sAA = fmaf(spA[i], w1A[i], sAA);
#pragma unroll
        for (int i = 0; i < SB; ++i) sAB = fmaf(spB[i], w1B[i], sAB);

        if (lane == 0)  cAin = 0.f;
        if (lane == 63) cBin = sBA;
        const float d0 = m0 - (sAA + cAin);
        const float d1 = m1 - (sAB + cBin);
        lp_prev = fmaf(d0, d0, d1*d1);

        // ---- backward; dAn/dBn latency hidden under momentum decay
        float dAn = __shfl_down(d0, 1);
        float dBn = __shfl_up(d1, 1);        // lane0: its w2B are all 0
        const float g0 = GC * d0, g1 = GC * d1;
#pragma unroll
        for (int i = 0; i < SA; ++i) bfA[i] *= 0.9f;   // indep of shfls
#pragma unroll
        for (int i = 0; i < SB; ++i) bfB[i] *= 0.9f;
        if (lane == 63) dAn = d1;
        const float gA = GC * dAn, gB = GC * dBn;
#pragma unroll
        for (int i = 0; i < SA; ++i) {
            float g = fmaf(g0, w1A[i], gA * w2A[i]);
            bfA[i] += g;
            float v = fmaf(-0.1f, bfA[i], spA[i]);
            spA[i] = v < 0.f ? 0.f : v;
        }
#pragma unroll
        for (int i = 0; i < SB; ++i) {
            float g = fmaf(g1, w1B[i], gB * w2B[i]);
            bfB[i] += g;
            float v = fmaf(-0.1f, bfB[i], spB[i]);
            spB[i] = v < 0.f ? 0.f : v;
        }
    }

    // ---- flush last iteration's loss partial
    if (!mode) {
        float lp = lp_prev;
#pragma unroll
        for (int m = 32; m; m >>= 1) lp += __shfl_xor(lp, m);
        if (lane == 0) bp[(niter - 1)*NROWS + r] = lp;
    }

    // ---- store out[batch, f, t] (scatter over f; each f stored once)
    float* og = out + ((size_t)batch*NSTFT)*TIME + t;
#pragma unroll
    for (int i = 0; i < SA; ++i)
        if (i < hA.y) og[(size_t)(hA.x + i)*TIME] = spA[i];
#pragma unroll
    for (int i = 0; i < SB; ++i)
        if (i < hB.y) og[(size_t)(hB.x + i)*TIME] = spB[i];
}

// ---- scan: 16 waves, one iteration each (coalesced float4) + stop logic ----
__global__ __launch_bounds__(1024) void scan_all(char* __restrict__ ws) {
    __shared__ float losses[MAXIT];
    const int tid = threadIdx.x, wave = tid >> 6, lane = tid & 63;
    const float* bp = (const float*)(ws + WS_BP_OFF);
    for (int it = wave; it < MAXIT; it += 16) {
        const float4* b4 = (const float4*)(bp + (size_t)it*NROWS);
        float s = 0.f;
#pragma unroll
        for (int j = 0; j < NROWS/256; ++j) {      // 8 x float4 per lane
            float4 v = b4[j*64 + lane];
            s += (v.x + v.y) + (v.z + v.w);
        }
#pragma unroll
        for (int m = 32; m; m >>= 1) s += __shfl_xor(s, m);
        if (lane == 0) losses[it] = s * (1.0f/(float)NROWS);
    }
    __syncthreads();
    if (tid == 0) {
        // reference stop logic: update applied on the stop iteration,
        // frozen after -> S = first stop index + 1, else MAXIT
        float prev = __builtin_inff();
        int S = MAXIT;
        for (int i = 0; i < MAXIT; ++i) {
            float l = losses[i];
            if (l < 1e-5f || fabsf(prev - l) < 1e-8f) { S = i + 1; break; }
            prev = l;
        }
        *(int*)(ws + WS_S_OFF) = S;
    }
}

extern "C" void kernel_launch(void* const* d_in, const int* in_sizes, int n_in,
                              void* d_out, int out_size, void* d_ws, size_t ws_size,
                              hipStream_t stream)
{
    const float* barkspec  = (const float*)d_in[0];
    const float* fb        = (const float*)d_in[1];
    const float* spec_init = (const float*)d_in[2];
    float* out = (float*)d_out;
    char* ws = (char*)d_ws;

    setup_all  <<<1, 512, 0, stream>>>(fb, ws);
    iter_kernel<<<NROWS, 64, 0, stream>>>(barkspec, spec_init, out, ws, 0);
    scan_all   <<<1, 1024, 0, stream>>>(ws);
    iter_kernel<<<NROWS, 64, 0, stream>>>(barkspec, spec_init, out, ws, 1);
}

// Round 8
// 104.865 us; speedup vs baseline: 1.2352x; 1.2352x over previous
//
#include <hip/hip_runtime.h>

// InverseBarkScale: 30-iter SGD with momentum inverting a bark filterbank.
// fb (513x128): freq f has taps only at columns (k1(f), k1(f)+1); k1 is
// monotone in f, so P(c) = {f : k1(f)=c} are contiguous and partition
// [0,513). |P(c)| <= ~3 for c<64, <= ~18 for c>=64.
//
// R8: R5-R7's fused single-block setup was a hidden 41us latency chain
// (one CU, 65 serial load->ballot rounds/wave; R6 "fix" never landed --
// it hid below the top-5 cutoff). Revert to R4's MULTI-BLOCK setup, one
// load-round per block spread across CUs, upgraded with the float2+shfl
// extraction (no scalar reloads):
//   setup_taps : 513 blocks x 1 wave -> ftab[f] = {k1,w1,-,w2}
//   setup_lanes: 128 blocks x 1 wave -> headers + packed weight tables
// iter (R7, kept): all-register, lane owns cols (l,127-l) + their primary
// freqs; 4 shfl/iter with latency hidden (deferred loss reduce, early carry
// shfls, momentum-decay overlap); no LDS, no barriers.
// Stop semantics: speculate 30 iters + loss log -> scan computes S ->
// repair launch only if S<30 (expected: immediate exit).
// Floor: harness d_ws poison fill (268MB ~41us @82% HBM) + input restore +
// graph gaps -- not controllable.

#define NSTFT 513
#define NBARK 128
#define BATCH 4
#define TIME  512
#define MAXIT 30
#define NROWS (BATCH*TIME)      // 2048 rows, 1 wave each
#define SA 6                    // A-side slots (cols 0..63, max ~3 real)
#define SB 20                   // B-side slots (cols 64..127, max ~18 real)

// d_ws layout (bytes); ~265 KB. Every field written before read each call.
#define WS_S_OFF   0                          // int: stop iteration S
#define WS_FT_OFF  256                        // float4[NSTFT]: {k1,w1,-,w2}
#define WS_HA_OFF  8464                       // int2[64]: A {fbase,cnt}
#define WS_HB_OFF  8976                       // int2[64]: B {fbase,cnt}
#define WS_WT_OFF  9488                       // float2[SA+SB][64]: {w1,w2}
#define WS_BP_OFF  22800                      // float[MAXIT][NROWS] partials

// ---- setup 1: per-freq taps, one wave per freq (1 load-round) ----
__global__ __launch_bounds__(64) void setup_taps(const float* __restrict__ fb,
                                                 char* __restrict__ ws) {
    const int f = blockIdx.x, lane = threadIdx.x;
    const float2 v = ((const float2*)(fb + (size_t)f * NBARK))[lane];
    unsigned long long mx = __ballot(v.x > 0.f);
    unsigned long long my = __ballot(v.y > 0.f);
    int kx = mx ? 2 * (__ffsll(mx) - 1)     : 999;
    int ky = my ? 2 * (__ffsll(my) - 1) + 1 : 999;
    int k1 = min(kx, ky);
    float w1 = 0.f, w2 = 0.f;
    if (k1 < NBARK) {
        float sx = __shfl(v.x, k1 >> 1);
        float sy = __shfl(v.y, k1 >> 1);
        w1 = (k1 & 1) ? sy : sx;
        const int k2 = k1 + 1;                   // taps are consecutive cols
        if (k2 < NBARK) {
            float tx = __shfl(v.x, k2 >> 1);
            float ty = __shfl(v.y, k2 >> 1);
            w2 = (k2 & 1) ? ty : tx;             // ==0 if row has 1 tap
        }
    } else {
        k1 = (f < 256) ? 0 : 127;                // all-zero row: edge attach
    }
    if (lane == 0) {
        float4 e;
        e.x = __int_as_float(k1); e.y = w1;
        e.z = 0.f;                e.w = w2;
        ((float4*)(ws + WS_FT_OFF))[f] = e;
    }
}

// ---- setup 2: per-column headers + packed weights, one wave per column ----
__global__ __launch_bounds__(64) void setup_lanes(char* __restrict__ ws) {
    const int c = blockIdx.x, lane = threadIdx.x;
    const float4* ftab = (const float4*)(ws + WS_FT_OFF);
    int fmin = 0x7fffffff, fmax = -1;
    float4 e9[9];
#pragma unroll
    for (int s = 0; s < 9; ++s) {
        int f = lane + 64*s;
        e9[s] = (f < NSTFT) ? ftab[f] : make_float4(__int_as_float(-1),0,0,0);
        if (f < NSTFT && __float_as_int(e9[s].x) == c) {
            fmin = min(fmin, f); fmax = max(fmax, f);
        }
    }
#pragma unroll
    for (int m = 32; m; m >>= 1) {
        fmin = min(fmin, __shfl_xor(fmin, m));
        fmax = max(fmax, __shfl_xor(fmax, m));
    }
    int cnt = (fmax >= 0) ? (fmax - fmin + 1) : 0;
    if (fmax < 0) fmin = 0;
    const int cap  = (c < 64) ? SA : SB;
    const int base = (c < 64) ? 0  : SA;
    const int lf   = (c < 64) ? c  : 127 - c;
    cnt = min(cnt, cap);
    if (lane == 0)
        ((int2*)(ws + (c < 64 ? WS_HA_OFF : WS_HB_OFF)))[lf] =
            make_int2(fmin, cnt);
    if (lane < cap) {
        float2 wv = make_float2(0.f, 0.f);
        if (lane < cnt) {
            float4 e = ftab[fmin + lane];        // L2-hit re-read, tiny
            wv = make_float2(e.y, e.w);
        }
        ((float2*)(ws + WS_WT_OFF))[(base + lane)*64 + lf] = wv;
    }
}

__global__ __launch_bounds__(64, 2) void
iter_kernel(const float* __restrict__ barkspec,
            const float* __restrict__ spec_init,
            float* __restrict__ out,
            char* __restrict__ ws, int mode)
{
    const int lane = threadIdx.x;            // single wave per block, no LDS

    int niter = MAXIT;
    if (mode) {
        int S = *(const volatile int*)(ws + WS_S_OFF);
        if (S >= MAXIT) return;              // expected path: no repair
        niter = S;
    }

    const int r     = blockIdx.x;
    const int batch = r >> 9;
    const int t     = r & (TIME - 1);

    // ---- per-lane tables -> registers ----
    const int2 hA = ((const int2*)(ws + WS_HA_OFF))[lane];
    const int2 hB = ((const int2*)(ws + WS_HB_OFF))[lane];
    const float2* wt = (const float2*)(ws + WS_WT_OFF);
    const float* spg = spec_init + ((size_t)batch*TIME + t)*NSTFT;

    float w1A[SA], w2A[SA], spA[SA], bfA[SA];
    float w1B[SB], w2B[SB], spB[SB], bfB[SB];
#pragma unroll
    for (int i = 0; i < SA; ++i) {
        float2 v = wt[i*64 + lane];
        w1A[i] = v.x; w2A[i] = v.y;
        spA[i] = (i < hA.y) ? spg[hA.x + i] : 0.f;
        bfA[i] = 0.f;
    }
#pragma unroll
    for (int i = 0; i < SB; ++i) {
        float2 v = wt[(SA + i)*64 + lane];
        w1B[i] = v.x; w2B[i] = v.y;
        spB[i] = (i < hB.y) ? spg[hB.x + i] : 0.f;
        bfB[i] = 0.f;
    }

    const float* bs = barkspec + (size_t)batch*NBARK*TIME + t;
    const float m0 = bs[(size_t)lane*TIME];          // col cA = lane
    const float m1 = bs[(size_t)(127 - lane)*TIME];  // col cB = 127-lane

    float* bp = (float*)(ws + WS_BP_OFF);
    const float GC = -2.0f / (float)NROWS;

    float lp_prev = 0.f;                     // loss partial of iteration it-1

#pragma unroll 2
    for (int it = 0; it < niter; ++it) {
        // ---- forward, carry-producing sums FIRST; issue their shfls early
        float sBA = 0.f, sBB = 0.f;
#pragma unroll
        for (int i = 0; i < SA; ++i) sBA = fmaf(spA[i], w2A[i], sBA);
#pragma unroll
        for (int i = 0; i < SB; ++i) sBB = fmaf(spB[i], w2B[i], sBB);
        float cAin = __shfl_up(sBA, 1);      // latency hidden under sAA/sAB
        float cBin = __shfl_down(sBB, 1);

        // ---- deferred loss reduction of iter it-1 (independent of iter it)
        if (!mode && it > 0) {
            float lp = lp_prev;
#pragma unroll
            for (int m = 32; m; m >>= 1) lp += __shfl_xor(lp, m);
            if (lane == 0) bp[(it - 1)*NROWS + r] = lp;  // fire-and-forget
        }

        float sAA = 0.f, sAB = 0.f;
#pragma unroll
        for (int i = 0; i < SA; ++i) sAA = fmaf(spA[i], w1A[i], sAA);
#pragma unroll
        for (int i = 0; i < SB; ++i) sAB = fmaf(spB[i], w1B[i], sAB);

        if (lane == 0)  cAin = 0.f;
        if (lane == 63) cBin = sBA;
        const float d0 = m0 - (sAA + cAin);
        const float d1 = m1 - (sAB + cBin);
        lp_prev = fmaf(d0, d0, d1*d1);

        // ---- backward; dAn/dBn latency hidden under momentum decay
        float dAn = __shfl_down(d0, 1);
        float dBn = __shfl_up(d1, 1);        // lane0: its w2B are all 0
        const float g0 = GC * d0, g1 = GC * d1;
#pragma unroll
        for (int i = 0; i < SA; ++i) bfA[i] *= 0.9f;   // indep of shfls
#pragma unroll
        for (int i = 0; i < SB; ++i) bfB[i] *= 0.9f;
        if (lane == 63) dAn = d1;
        const float gA = GC * dAn, gB = GC * dBn;
#pragma unroll
        for (int i = 0; i < SA; ++i) {
            float g = fmaf(g0, w1A[i], gA * w2A[i]);
            bfA[i] += g;
            float v = fmaf(-0.1f, bfA[i], spA[i]);
            spA[i] = v < 0.f ? 0.f : v;
        }
#pragma unroll
        for (int i = 0; i < SB; ++i) {
            float g = fmaf(g1, w1B[i], gB * w2B[i]);
            bfB[i] += g;
            float v = fmaf(-0.1f, bfB[i], spB[i]);
            spB[i] = v < 0.f ? 0.f : v;
        }
    }

    // ---- flush last iteration's loss partial
    if (!mode) {
        float lp = lp_prev;
#pragma unroll
        for (int m = 32; m; m >>= 1) lp += __shfl_xor(lp, m);
        if (lane == 0) bp[(niter - 1)*NROWS + r] = lp;
    }

    // ---- store out[batch, f, t] (scatter over f; each f stored once)
    float* og = out + ((size_t)batch*NSTFT)*TIME + t;
#pragma unroll
    for (int i = 0; i < SA; ++i)
        if (i < hA.y) og[(size_t)(hA.x + i)*TIME] = spA[i];
#pragma unroll
    for (int i = 0; i < SB; ++i)
        if (i < hB.y) og[(size_t)(hB.x + i)*TIME] = spB[i];
}

// ---- scan: 16 waves, one iteration each (coalesced float4) + stop logic ----
__global__ __launch_bounds__(1024) void scan_all(char* __restrict__ ws) {
    __shared__ float losses[MAXIT];
    const int tid = threadIdx.x, wave = tid >> 6, lane = tid & 63;
    const float* bp = (const float*)(ws + WS_BP_OFF);
    for (int it = wave; it < MAXIT; it += 16) {
        const float4* b4 = (const float4*)(bp + (size_t)it*NROWS);
        float s = 0.f;
#pragma unroll
        for (int j = 0; j < NROWS/256; ++j) {      // 8 x float4 per lane
            float4 v = b4[j*64 + lane];
            s += (v.x + v.y) + (v.z + v.w);
        }
#pragma unroll
        for (int m = 32; m; m >>= 1) s += __shfl_xor(s, m);
        if (lane == 0) losses[it] = s * (1.0f/(float)NROWS);
    }
    __syncthreads();
    if (tid == 0) {
        // reference stop logic: update applied on the stop iteration,
        // frozen after -> S = first stop index + 1, else MAXIT
        float prev = __builtin_inff();
        int S = MAXIT;
        for (int i = 0; i < MAXIT; ++i) {
            float l = losses[i];
            if (l < 1e-5f || fabsf(prev - l) < 1e-8f) { S = i + 1; break; }
            prev = l;
        }
        *(int*)(ws + WS_S_OFF) = S;
    }
}

extern "C" void kernel_launch(void* const* d_in, const int* in_sizes, int n_in,
                              void* d_out, int out_size, void* d_ws, size_t ws_size,
                              hipStream_t stream)
{
    const float* barkspec  = (const float*)d_in[0];
    const float* fb        = (const float*)d_in[1];
    const float* spec_init = (const float*)d_in[2];
    float* out = (float*)d_out;
    char* ws = (char*)d_ws;

    setup_taps <<<NSTFT, 64, 0, stream>>>(fb, ws);
    setup_lanes<<<NBARK, 64, 0, stream>>>(ws);
    iter_kernel<<<NROWS, 64, 0, stream>>>(barkspec, spec_init, out, ws, 0);
    scan_all   <<<1, 1024, 0, stream>>>(ws);
    iter_kernel<<<NROWS, 64, 0, stream>>>(barkspec, spec_init, out, ws, 1);
}